// Round 13
// baseline (222.570 us; speedup 1.0000x reference)
//
#include <hip/hip_runtime.h>

// SpanRepresentation R12: DIAGNOSTIC double-write build.
// Purpose: our dispatch has never appeared in the top-5 (poison fills ~122us
// dominate), so we've never seen our own counters. Running the store phase
// twice (~160us) forces our dispatch into the top-5 with FETCH/WRITE/VALUBusy/
// Occupancy visible. Second pass writes identical bytes => still correct.
// Discriminates: RFO/write-allocate (FETCH huge) vs genuine store cap
// (WRITE=2x202MB, FETCH small) vs issue/occupancy limits.

typedef float f4 __attribute__((ext_vector_type(4)));

#define L_DIM 512
#define S_TOT 4068
#define ROW4  389
#define D4    192

// cw[w-1] = {0,512,1023,1533,2042,2550,3057,3563}, packed 4x16b per u64
#define CW_LO ((1533ull << 48) | (1023ull << 32) | (512ull << 16) | 0ull)
#define CW_HI ((3563ull << 48) | (3057ull << 32) | (2550ull << 16) | 2042ull)
__device__ __forceinline__ int cw_of(int k) {  // k = w-1, 0..7
    return (int)(((k < 4 ? CW_LO : CW_HI) >> (16 * (k & 3))) & 0xFFFF);
}

__global__ __launch_bounds__(256) void span_rep_lds_x2(
    const f4* __restrict__ x,
    const f4* __restrict__ we,
    f4* __restrict__ out)
{
    __shared__ f4 lx[D4];   // the x row (3 KB)
    __shared__ f4 lw[40];   // wemb rows for w=1..8 (5 f4 each)

    const int r = blockIdx.x;
    const int b = blockIdx.y;
    const int t = (int)threadIdx.x;

    // ---- phase 1: stage (the only global loads in the kernel) ----
    if (t < D4) {
        lx[t] = x[((size_t)b * L_DIM + r) * D4 + t];
    } else if (t < D4 + 40) {
        const int u = t - D4;              // 0..39
        const int w = u / 5 + 1;           // 1..8
        const int col = u - (w - 1) * 5;   // 0..4
        const int bucket = (int)((0x765543210ull >> (4 * w)) & 0xF);
        lw[u] = we[bucket * 5 + col];
    }
    __syncthreads();

    const size_t outB = (size_t)b * S_TOT;

    // ---- phase 2, executed TWICE (idempotent; barrier blocks store-merge) ----
    for (int pass = 0; pass < 2; ++pass) {
        #pragma unroll
        for (int i = 0; i < 12; ++i) {     // 12*256 = 3072 = 16 segs * 192
            const int u = i * 256 + t;
            const int q = (u >> 6) / 3;    // segment 0..15
            const int e = u - q * 192;     // 0..191
            const int w = (q & 7) + 1;     // width 1..8
            const int cw = cw_of(q & 7);
            if (q < 8) {                   // start-role
                if (r + w <= L_DIM)
                    out[(outB + cw + r) * ROW4 + e] = lx[e];
            } else {                       // end-role
                if (r >= w - 1)
                    out[(outB + cw + r - w + 1) * ROW4 + D4 + e] = lx[e];
            }
        }
        // wemb tail: 40 float4
        if (t < 40) {
            const int w = t / 5 + 1;
            const int col = t - (w - 1) * 5;
            if (r + w <= L_DIM)
                out[(outB + cw_of(w - 1) + r) * ROW4 + 2 * D4 + col] = lw[t];
        }
        __syncthreads();   // memory fence: keeps both passes' stores live
    }
}

extern "C" void kernel_launch(void* const* d_in, const int* in_sizes, int n_in,
                              void* d_out, int out_size, void* d_ws, size_t ws_size,
                              hipStream_t stream) {
    const f4* x  = (const f4*)d_in[0];  // (8, 512, 768) f32
    const f4* we = (const f4*)d_in[1];  // (14, 20) f32
    f4* out = (f4*)d_out;               // (8, 4068, 1556) f32

    dim3 grid(L_DIM, 8);                // 4096 blocks, one per (r,b)
    span_rep_lds_x2<<<grid, 256, 0, stream>>>(x, we, out);
}